// Round 2
// baseline (1689.877 us; speedup 1.0000x reference)
//
#include <hip/hip_runtime.h>
#include <math.h>

// ---------------------------------------------------------------------------
// GatedNNMF: h=gelu(x@U_w^T+U_b); z1,z2=split(h); xm=relu(LN(z2));
// NMF2D(xm, bases, 6 steps) -> z2r; out=(z1*z2r)@V_w^T+V_b
// B=8 S=1024 F=1024 FFN=4096 Nc=2048 R=64
// Interface: input dtype auto-detected (fp32 vs bf16); OUTPUT dtype follows
// input dtype (reference is pure fp32 -> primary path stores float).
// ---------------------------------------------------------------------------

typedef __bf16 bf16;
typedef bf16 bf16x4 __attribute__((ext_vector_type(4)));
typedef bf16 bf16x8 __attribute__((ext_vector_type(8)));
typedef float f32x4 __attribute__((ext_vector_type(4)));

#define NMF_EPS 1e-6f
#define LNEPS   1e-5f

// ---------------- dtype probe: fp32 data viewed as bf16 -> huge/NaN ---------
__global__ __launch_bounds__(256) void detect_dtype(const void* x, int* flag) {
    __shared__ int bad_sh;
    if (threadIdx.x == 0) bad_sh = 0;
    __syncthreads();
    const bf16* p = (const bf16*)x;
    int bad = 0;
    for (int i = threadIdx.x; i < 1024; i += 256) {
        float f = (float)p[i];
        if (!(fabsf(f) < 1000.f)) bad = 1;   // catches NaN too
    }
    if (bad) atomicOr(&bad_sh, 1);
    __syncthreads();
    if (threadIdx.x == 0) *flag = bad_sh;    // 1 => inputs are fp32
}

// normalize any input to bf16 arena (n4 = n/4)
__global__ __launch_bounds__(256) void conv_in(const void* src, bf16* dst, int n4,
                                               const int* flag) {
    const int is_f32 = *flag;
    for (int i = blockIdx.x * 256 + threadIdx.x; i < n4; i += gridDim.x * 256) {
        bf16x4 o;
        if (is_f32) {
            f32x4 v = ((const f32x4*)src)[i];
            o[0] = (bf16)v[0]; o[1] = (bf16)v[1]; o[2] = (bf16)v[2]; o[3] = (bf16)v[3];
        } else {
            o = ((const bf16x4*)src)[i];
        }
        ((bf16x4*)dst)[i] = o;
    }
}

// ---------------- MFMA GEMM: C = A(M,K) @ B(N,K)^T, bf16 in, fp32 acc -------
// EPI 0: v=gelu(v+bias); n<2048 -> o0 (bf16 z1), else o1 (bf16 z2), both (M,2048)
// EPI 1: v+=bias; store to outf (fp32) if *flag else outb (bf16), (M,N)
template <int EPI>
__global__ __launch_bounds__(256)
void gemm_bt(const bf16* __restrict__ A, const bf16* __restrict__ B,
             const bf16* __restrict__ bias,
             bf16* __restrict__ o0, bf16* __restrict__ o1,
             float* __restrict__ outf, bf16* __restrict__ outb,
             int K, int N, const int* __restrict__ flag) {
    __shared__ bf16 As[128 * 32];
    __shared__ bf16 Bs[128 * 32];
    const int tid = threadIdx.x;
    const int bm = blockIdx.x, bn = blockIdx.y;
    const bf16* Ab = A + (size_t)bm * 128 * K;
    const bf16* Bb = B + (size_t)bn * 128 * K;
    const int w = tid >> 6, lane = tid & 63, lm = lane & 15, lq = lane >> 4;
    const int m_off = (w >> 1) * 64, n_off = (w & 1) * 64;
    const int of32 = (EPI == 1) ? *flag : 0;
    f32x4 acc[4][4];
#pragma unroll
    for (int i = 0; i < 4; i++)
#pragma unroll
        for (int j = 0; j < 4; j++) { acc[i][j][0]=0.f; acc[i][j][1]=0.f; acc[i][j][2]=0.f; acc[i][j][3]=0.f; }

    const int r0 = tid * 8;            // element offset, 8 bf16 = 16B per round
    const int row0 = r0 >> 5, col0 = r0 & 31;
    for (int k0 = 0; k0 < K; k0 += 32) {
        __syncthreads();
        *(int4*)(&As[r0])        = *(const int4*)(Ab + (size_t)row0 * K        + k0 + col0);
        *(int4*)(&As[r0 + 2048]) = *(const int4*)(Ab + (size_t)(row0 + 64) * K + k0 + col0);
        *(int4*)(&Bs[r0])        = *(const int4*)(Bb + (size_t)row0 * K        + k0 + col0);
        *(int4*)(&Bs[r0 + 2048]) = *(const int4*)(Bb + (size_t)(row0 + 64) * K + k0 + col0);
        __syncthreads();
        bf16x8 af[4], bg[4];
#pragma unroll
        for (int i = 0; i < 4; i++) af[i] = *(const bf16x8*)&As[(m_off + i * 16 + lm) * 32 + lq * 8];
#pragma unroll
        for (int j = 0; j < 4; j++) bg[j] = *(const bf16x8*)&Bs[(n_off + j * 16 + lm) * 32 + lq * 8];
#pragma unroll
        for (int i = 0; i < 4; i++)
#pragma unroll
            for (int j = 0; j < 4; j++)
                acc[i][j] = __builtin_amdgcn_mfma_f32_16x16x32_bf16(af[i], bg[j], acc[i][j], 0, 0, 0);
    }
    const int gm0 = bm * 128 + m_off, gn0 = bn * 128 + n_off;
#pragma unroll
    for (int i = 0; i < 4; i++) {
#pragma unroll
        for (int j = 0; j < 4; j++) {
            const int gn = gn0 + j * 16 + lm;
            const float bv = (float)bias[gn];
#pragma unroll
            for (int e = 0; e < 4; e++) {
                const int gm = gm0 + i * 16 + lq * 4 + e;
                float v = acc[i][j][e] + bv;
                if (EPI == 0) {
                    v = 0.5f * v * (1.f + erff(v * 0.70710678118654752f));
                    if (gn < 2048) o0[(size_t)gm * 2048 + gn] = (bf16)v;
                    else           o1[(size_t)gm * 2048 + (gn - 2048)] = (bf16)v;
                } else {
                    if (of32) outf[(size_t)gm * N + gn] = v;
                    else      outb[(size_t)gm * N + gn] = (bf16)v;
                }
            }
        }
    }
}

// ---------------- LayerNorm(2048) + ReLU, in-place bf16 ---------------------
__global__ __launch_bounds__(256)
void ln_relu(bf16* __restrict__ z, const bf16* __restrict__ g, const bf16* __restrict__ b) {
    const int row = blockIdx.x;
    bf16* zr = z + (size_t)row * 2048;
    const int t = threadIdx.x;
    bf16x4 a0 = *(bf16x4*)(zr + t * 4);
    bf16x4 a1 = *(bf16x4*)(zr + 1024 + t * 4);
    float v0[4], v1[4];
#pragma unroll
    for (int i = 0; i < 4; i++) { v0[i] = (float)a0[i]; v1[i] = (float)a1[i]; }
    float s = 0.f, q = 0.f;
#pragma unroll
    for (int i = 0; i < 4; i++) { s += v0[i] + v1[i]; q += v0[i] * v0[i] + v1[i] * v1[i]; }
#pragma unroll
    for (int off = 32; off >= 1; off >>= 1) { s += __shfl_down(s, off); q += __shfl_down(q, off); }
    __shared__ float red[8];
    __shared__ float mv[2];
    const int wv = t >> 6;
    if ((t & 63) == 0) { red[wv] = s; red[4 + wv] = q; }
    __syncthreads();
    if (t == 0) {
        float S = red[0] + red[1] + red[2] + red[3];
        float Q = red[4] + red[5] + red[6] + red[7];
        float mu = S * (1.f / 2048.f);
        float var = Q * (1.f / 2048.f) - mu * mu;
        mv[0] = mu; mv[1] = rsqrtf(var + LNEPS);
    }
    __syncthreads();
    const float mu = mv[0], ri = mv[1];
#pragma unroll
    for (int i = 0; i < 4; i++) {
        int c0 = t * 4 + i, c1 = 1024 + t * 4 + i;
        a0[i] = (bf16)fmaxf((v0[i] - mu) * ri * (float)g[c0] + (float)b[c0], 0.f);
        a1[i] = (bf16)fmaxf((v1[i] - mu) * ri * (float)g[c1] + (float)b[c1], 0.f);
    }
    *(bf16x4*)(zr + t * 4) = a0;
    *(bf16x4*)(zr + 1024 + t * 4) = a1;
}

// ---------------- broadcast bases0 (bf16) -> per-batch fp32 -----------------
__global__ __launch_bounds__(256)
void bases_init(const bf16* __restrict__ b0, float* __restrict__ bases) {
    const int idx = (blockIdx.x * 256 + threadIdx.x) * 4;  // over 8*65536
    const int i = idx & 65535;
    f32x4 v;
#pragma unroll
    for (int j = 0; j < 4; j++) v[j] = (float)b0[i + j];
    *(f32x4*)(bases + idx) = v;
}

// ---------------- coef0 = softmax_r( xm^T @ bases ) -------------------------
__global__ __launch_bounds__(256)
void coef_init(const bf16* __restrict__ xm, const float* __restrict__ bases,
               float* __restrict__ coef) {
    const int n0 = blockIdx.x * 64, b = blockIdx.y;
    const bf16*  X  = xm    + (size_t)b * 1024 * 2048;
    const float* Bb = bases + (size_t)b * 1024 * 64;
    __shared__ float xs[16 * 64];
    __shared__ float bs[16 * 64];
    __shared__ float num_sh[64 * 68];
    __shared__ float mrow[64], srow[64];
    const int t = threadIdx.x;
    const int tn = t & 15, tr = t >> 4;
    const int lrow = t >> 4, lcol = (t & 15) * 4;
    float acc[4][4] = {};
    for (int d0 = 0; d0 < 1024; d0 += 16) {
        __syncthreads();
        {
            bf16x4 xv = *(const bf16x4*)(X + (size_t)(d0 + lrow) * 2048 + n0 + lcol);
            f32x4 xf;
#pragma unroll
            for (int j = 0; j < 4; j++) xf[j] = (float)xv[j];
            *(f32x4*)&xs[lrow * 64 + lcol] = xf;
            *(f32x4*)&bs[lrow * 64 + lcol] = *(const f32x4*)(Bb + (size_t)(d0 + lrow) * 64 + lcol);
        }
        __syncthreads();
#pragma unroll
        for (int dd = 0; dd < 16; dd++) {
            f32x4 a = *(f32x4*)&xs[dd * 64 + tn * 4];
            f32x4 c = *(f32x4*)&bs[dd * 64 + tr * 4];
#pragma unroll
            for (int ni = 0; ni < 4; ni++)
#pragma unroll
                for (int rj = 0; rj < 4; rj++) acc[ni][rj] += a[ni] * c[rj];
        }
    }
    __syncthreads();
#pragma unroll
    for (int ni = 0; ni < 4; ni++)
#pragma unroll
        for (int rj = 0; rj < 4; rj++) num_sh[(tn * 4 + ni) * 68 + tr * 4 + rj] = acc[ni][rj];
    __syncthreads();
    if (t < 64) {
        float m = -1e30f;
        for (int r = 0; r < 64; r++) m = fmaxf(m, num_sh[t * 68 + r]);
        float ss = 0.f;
        for (int r = 0; r < 64; r++) ss += expf(num_sh[t * 68 + r] - m);
        mrow[t] = m; srow[t] = ss;
    }
    __syncthreads();
    float* C = coef + (size_t)b * 2048 * 64;
#pragma unroll
    for (int ni = 0; ni < 4; ni++) {
        const int n = tn * 4 + ni;
        const float m = mrow[n], inv = 1.f / srow[n];
        f32x4 o;
#pragma unroll
        for (int rj = 0; rj < 4; rj++) o[rj] = expf(acc[ni][rj] - m) * inv;
        *(f32x4*)(C + (size_t)(n0 + n) * 64 + tr * 4) = o;
    }
}

// ---------------- Gram: out[b] += V[b,chunk*128:+128,:]^T @ (same) ----------
__global__ __launch_bounds__(256)
void gram128(const float* __restrict__ V, size_t batch_stride, float* __restrict__ out) {
    const int b = blockIdx.y;
    const float* Vb = V + (size_t)b * batch_stride + (size_t)blockIdx.x * 128 * 64;
    __shared__ float vs[32 * 64];
    const int t = threadIdx.x;
    const int tr = t & 15, ts = t >> 4;
    const int lrow = t >> 3, lcol = (t & 7) * 8;
    float acc[4][4] = {};
    for (int r0 = 0; r0 < 128; r0 += 32) {
        __syncthreads();
        *(f32x4*)&vs[lrow * 64 + lcol]     = *(const f32x4*)(Vb + (size_t)(r0 + lrow) * 64 + lcol);
        *(f32x4*)&vs[lrow * 64 + lcol + 4] = *(const f32x4*)(Vb + (size_t)(r0 + lrow) * 64 + lcol + 4);
        __syncthreads();
#pragma unroll
        for (int dd = 0; dd < 32; dd++) {
            f32x4 a = *(f32x4*)&vs[dd * 64 + tr * 4];
            f32x4 c = *(f32x4*)&vs[dd * 64 + ts * 4];
#pragma unroll
            for (int i = 0; i < 4; i++)
#pragma unroll
                for (int j = 0; j < 4; j++) acc[i][j] += a[i] * c[j];
        }
    }
    float* O = out + (size_t)b * 4096;
#pragma unroll
    for (int i = 0; i < 4; i++)
#pragma unroll
        for (int j = 0; j < 4; j++) atomicAdd(O + (tr * 4 + i) * 64 + ts * 4 + j, acc[i][j]);
}

// ------- coef[n,r] *= (xm^T@bases)[n,r] / (coef@btb + eps)[n,r] -------------
__global__ __launch_bounds__(256)
void coef_update(const bf16* __restrict__ xm, const float* __restrict__ bases,
                 const float* __restrict__ btb, float* __restrict__ coef) {
    const int n0 = blockIdx.x * 64, b = blockIdx.y;
    const bf16*  X  = xm    + (size_t)b * 1024 * 2048;
    const float* Bb = bases + (size_t)b * 1024 * 64;
    const float* G  = btb   + (size_t)b * 4096;
    float* C = coef + (size_t)b * 2048 * 64;
    __shared__ float xs[16 * 64];
    __shared__ float bs[16 * 64];
    __shared__ float gs[4096];       // btb[s][r] flat
    __shared__ float cf[64 * 68];    // coef tile, padded
    const int t = threadIdx.x;
    const int tn = t & 15, tr = t >> 4;
    {
        const int r = t >> 2, c = (t & 3) * 16;
#pragma unroll
        for (int i = 0; i < 4; i++)
            *(f32x4*)&gs[r * 64 + c + i * 4] = *(const f32x4*)(G + r * 64 + c + i * 4);
#pragma unroll
        for (int i = 0; i < 4; i++)
            *(f32x4*)&cf[r * 68 + c + i * 4] = *(const f32x4*)(C + (size_t)(n0 + r) * 64 + c + i * 4);
    }
    const int lrow = t >> 4, lcol = (t & 15) * 4;
    float acc[4][4] = {};
    for (int d0 = 0; d0 < 1024; d0 += 16) {
        __syncthreads();
        {
            bf16x4 xv = *(const bf16x4*)(X + (size_t)(d0 + lrow) * 2048 + n0 + lcol);
            f32x4 xf;
#pragma unroll
            for (int j = 0; j < 4; j++) xf[j] = (float)xv[j];
            *(f32x4*)&xs[lrow * 64 + lcol] = xf;
            *(f32x4*)&bs[lrow * 64 + lcol] = *(const f32x4*)(Bb + (size_t)(d0 + lrow) * 64 + lcol);
        }
        __syncthreads();
#pragma unroll
        for (int dd = 0; dd < 16; dd++) {
            f32x4 a = *(f32x4*)&xs[dd * 64 + tn * 4];
            f32x4 c = *(f32x4*)&bs[dd * 64 + tr * 4];
#pragma unroll
            for (int ni = 0; ni < 4; ni++)
#pragma unroll
                for (int rj = 0; rj < 4; rj++) acc[ni][rj] += a[ni] * c[rj];
        }
    }
    float den[4][4] = {};
#pragma unroll 8
    for (int s = 0; s < 64; s++) {
        f32x4 g4 = *(f32x4*)&gs[s * 64 + tr * 4];
        float c4[4];
#pragma unroll
        for (int ni = 0; ni < 4; ni++) c4[ni] = cf[(tn * 4 + ni) * 68 + s];
#pragma unroll
        for (int ni = 0; ni < 4; ni++)
#pragma unroll
            for (int rj = 0; rj < 4; rj++) den[ni][rj] += c4[ni] * g4[rj];
    }
#pragma unroll
    for (int ni = 0; ni < 4; ni++) {
        const int n = tn * 4 + ni;
        f32x4 o;
#pragma unroll
        for (int rj = 0; rj < 4; rj++)
            o[rj] = cf[n * 68 + tr * 4 + rj] * acc[ni][rj] / (den[ni][rj] + NMF_EPS);
        *(f32x4*)(C + (size_t)(n0 + n) * 64 + tr * 4) = o;
    }
}

// ------- bases[d,r] *= (xm@coef)[d,r] / (bases@ctc + eps)[d,r] --------------
__global__ __launch_bounds__(256)
void bases_update(const bf16* __restrict__ xm, const float* __restrict__ coef,
                  const float* __restrict__ ctc, float* __restrict__ bases) {
    const int d0 = blockIdx.x * 64, b = blockIdx.y;
    const bf16*  X  = xm   + (size_t)b * 1024 * 2048;
    const float* Cf = coef + (size_t)b * 2048 * 64;
    const float* G  = ctc  + (size_t)b * 4096;
    float* Bb = bases + (size_t)b * 1024 * 64;
    __shared__ float xs[64 * 33];    // [d][n] padded (scalar stores)
    __shared__ float cs[32 * 64];    // [n][r]
    __shared__ float gs[4096];       // ctc[s][r]
    __shared__ float bo[64 * 68];    // old bases tile, padded
    const int t = threadIdx.x;
    const int tr = t & 15, td = t >> 4;
    {
        const int r = t >> 2, c = (t & 3) * 16;
#pragma unroll
        for (int i = 0; i < 4; i++)
            *(f32x4*)&gs[r * 64 + c + i * 4] = *(const f32x4*)(G + r * 64 + c + i * 4);
#pragma unroll
        for (int i = 0; i < 4; i++)
            *(f32x4*)&bo[r * 68 + c + i * 4] = *(const f32x4*)(Bb + (size_t)(d0 + r) * 64 + c + i * 4);
    }
    float acc[4][4] = {};  // [di][rj]
    const int xrow = t >> 2, xcol = (t & 3) * 8;
    const int crow = t >> 3, ccol = (t & 7) * 8;
    for (int nt = 0; nt < 2048; nt += 32) {
        __syncthreads();
        {
            bf16x8 u = *(const bf16x8*)(X + (size_t)(d0 + xrow) * 2048 + nt + xcol);
#pragma unroll
            for (int i = 0; i < 8; i++) xs[xrow * 33 + xcol + i] = (float)u[i];
            *(f32x4*)&cs[crow * 64 + ccol]     = *(const f32x4*)(Cf + (size_t)(nt + crow) * 64 + ccol);
            *(f32x4*)&cs[crow * 64 + ccol + 4] = *(const f32x4*)(Cf + (size_t)(nt + crow) * 64 + ccol + 4);
        }
        __syncthreads();
#pragma unroll 4
        for (int nn = 0; nn < 32; nn++) {
            float a4[4];
#pragma unroll
            for (int di = 0; di < 4; di++) a4[di] = xs[(td * 4 + di) * 33 + nn];
            f32x4 c4 = *(f32x4*)&cs[nn * 64 + tr * 4];
#pragma unroll
            for (int di = 0; di < 4; di++)
#pragma unroll
                for (int rj = 0; rj < 4; rj++) acc[di][rj] += a4[di] * c4[rj];
        }
    }
    float den[4][4] = {};
#pragma unroll 8
    for (int s = 0; s < 64; s++) {
        f32x4 g4 = *(f32x4*)&gs[s * 64 + tr * 4];
        float b4[4];
#pragma unroll
        for (int di = 0; di < 4; di++) b4[di] = bo[(td * 4 + di) * 68 + s];
#pragma unroll
        for (int di = 0; di < 4; di++)
#pragma unroll
            for (int rj = 0; rj < 4; rj++) den[di][rj] += b4[di] * g4[rj];
    }
#pragma unroll
    for (int di = 0; di < 4; di++) {
        const int d = td * 4 + di;
        f32x4 o;
#pragma unroll
        for (int rj = 0; rj < 4; rj++)
            o[rj] = bo[d * 68 + tr * 4 + rj] * acc[di][rj] / (den[di][rj] + NMF_EPS);
        *(f32x4*)(Bb + (size_t)(d0 + d) * 64 + tr * 4) = o;
    }
}

// ------- A[s,n] = bf16( z1[s,n] * sum_r bases[s,r]*coef[n,r] ), in-place ----
__global__ __launch_bounds__(256)
void recon_gate(bf16* __restrict__ z1A, const float* __restrict__ bases,
                const float* __restrict__ coef) {
    const int n0 = blockIdx.x * 64, s0 = blockIdx.y * 64, b = blockIdx.z;
    const float* Bb = bases + (size_t)b * 1024 * 64 + (size_t)s0 * 64;
    const float* Cf = coef  + (size_t)b * 2048 * 64 + (size_t)n0 * 64;
    __shared__ float bsh[64 * 68];
    __shared__ float csh[64 * 65];
    const int t = threadIdx.x;
    {
        const int r = t >> 2, c = (t & 3) * 16;
#pragma unroll
        for (int i = 0; i < 4; i++)
            *(f32x4*)&bsh[r * 68 + c + i * 4] = *(const f32x4*)(Bb + r * 64 + c + i * 4);
#pragma unroll
        for (int i = 0; i < 16; i++) csh[r * 65 + c + i] = Cf[r * 64 + c + i];
    }
    __syncthreads();
    const int tn = t & 15, ts = t >> 4;
    float acc[4][4] = {};  // [si][ni]
#pragma unroll 8
    for (int r = 0; r < 64; r++) {
        float bv[4], cv[4];
#pragma unroll
        for (int si = 0; si < 4; si++) bv[si] = bsh[(ts * 4 + si) * 68 + r];
#pragma unroll
        for (int ni = 0; ni < 4; ni++) cv[ni] = csh[(tn * 4 + ni) * 65 + r];
#pragma unroll
        for (int si = 0; si < 4; si++)
#pragma unroll
            for (int ni = 0; ni < 4; ni++) acc[si][ni] += bv[si] * cv[ni];
    }
    const size_t rowbase = (size_t)b * 1024 + s0;
#pragma unroll
    for (int si = 0; si < 4; si++) {
        const size_t row = rowbase + ts * 4 + si;
        bf16* p = z1A + row * 2048 + n0 + tn * 4;
        bf16x4 zv = *(bf16x4*)p;
        bf16x4 o;
#pragma unroll
        for (int ni = 0; ni < 4; ni++) o[ni] = (bf16)((float)zv[ni] * acc[si][ni]);
        *(bf16x4*)p = o;
    }
}

// ---------------------------------------------------------------------------
extern "C" void kernel_launch(void* const* d_in, const int* in_sizes, int n_in,
                              void* d_out, int out_size, void* d_ws, size_t ws_size,
                              hipStream_t stream) {
    (void)in_sizes; (void)n_in; (void)out_size; (void)ws_size;
    char* ws = (char*)d_ws;
    bf16*  z1A   = (bf16*)(ws);                   // 33554432 B (z1 -> gated A)
    bf16*  xmB   = (bf16*)(ws + 33554432);        // 33554432 B (z2 -> xm)
    float* bases = (float*)(ws + 67108864);       // 2097152 B
    float* coef  = (float*)(ws + 69206016);       // 4194304 B
    float* btb   = (float*)(ws + 73400320);       // 131072 B
    float* ctc   = (float*)(ws + 73531392);       // 131072 B
    // bf16 input arena (normalized dtype)
    char*  ar    = ws + 73662464;
    bf16* xc   = (bf16*)(ar);                 // 8388608 el
    bf16* Uwc  = (bf16*)(ar + 16777216);      // 4194304
    bf16* Ubc  = (bf16*)(ar + 25165824);      // 4096
    bf16* lngc = (bf16*)(ar + 25174016);      // 2048
    bf16* lnbc = (bf16*)(ar + 25178112);      // 2048
    bf16* b0c  = (bf16*)(ar + 25182208);      // 65536
    bf16* Vwc  = (bf16*)(ar + 25313280);      // 2097152
    bf16* Vbc  = (bf16*)(ar + 29507584);      // 1024
    int*  dflag = (int*)(ar + 29509632);
    // total ws usage: ~103.2 MB

    detect_dtype<<<1, 256, 0, stream>>>(d_in[0], dflag);
    const int   ns[8] = {8388608, 4194304, 4096, 2048, 2048, 65536, 2097152, 1024};
    bf16*       ds[8] = {xc, Uwc, Ubc, lngc, lnbc, b0c, Vwc, Vbc};
    for (int i = 0; i < 8; i++) {
        int n4 = ns[i] / 4;
        int grid = (n4 + 255) / 256; if (grid > 4096) grid = 4096;
        conv_in<<<grid, 256, 0, stream>>>(d_in[i], ds[i], n4, dflag);
    }

    // 1) h = gelu(x @ U_w^T + U_b) -> z1 (bf16) | z2 (bf16, xmB)
    gemm_bt<0><<<dim3(64, 32), 256, 0, stream>>>(xc, Uwc, Ubc, z1A, xmB,
                                                 nullptr, nullptr, 1024, 4096, nullptr);
    // 2) xm = relu(LN(z2)) in place
    ln_relu<<<dim3(8192), 256, 0, stream>>>(xmB, lngc, lnbc);
    // 3) NMF (fp32 state)
    bases_init<<<dim3(512), 256, 0, stream>>>(b0c, bases);
    coef_init<<<dim3(32, 8), 256, 0, stream>>>(xmB, bases, coef);
    for (int it = 0; it < 7; ++it) {
        hipMemsetAsync(btb, 0, 8 * 4096 * 4, stream);
        gram128<<<dim3(8, 8), 256, 0, stream>>>(bases, 1024 * 64, btb);
        coef_update<<<dim3(32, 8), 256, 0, stream>>>(xmB, bases, btb, coef);
        if (it < 6) {
            hipMemsetAsync(ctc, 0, 8 * 4096 * 4, stream);
            gram128<<<dim3(16, 8), 256, 0, stream>>>(coef, 2048 * 64, ctc);
            bases_update<<<dim3(16, 8), 256, 0, stream>>>(xmB, coef, ctc, bases);
        }
    }
    // 4) A = z1 * (bases @ coef^T), in place over z1A
    recon_gate<<<dim3(32, 16, 8), 256, 0, stream>>>(z1A, bases, coef);
    // 5) out = A @ V_w^T + V_b   (fp32 out if inputs were fp32, else bf16)
    gemm_bt<1><<<dim3(64, 8), 256, 0, stream>>>(z1A, Vwc, Vbc, nullptr, nullptr,
                                                (float*)d_out, (bf16*)d_out,
                                                2048, 1024, dflag);
}